// Round 3
// baseline (252.683 us; speedup 1.0000x reference)
//
#include <hip/hip_runtime.h>
#include <cstdint>
#include <cstddef>

#define S 8192
#define Dm 1024
#define E 64
#define CAP 128
#define SEC 67108864ull   // S*E*CAP
// out layout (float32 elements):
//   [0] l_aux | [1,1+SEC) combine | [1+SEC,1+2SEC) dispatch | [1+2SEC,+64) counts
// out_size = 1 + 2*SEC + 64 = 134,217,793 floats; fill covers N4*4 = 134,217,792,
// the one leftover element is exp_counts[63], written unconditionally by k_scan.

#define GEMM_BLOCKS 512   // 64 token-tiles x 8 K-slices
#define FILL_BLOCKS 4096
#define NTHR 128
#define TOKB 128

// ---------------- K1: fused K-split GEMM + 537MB zero-fill ----------------
// GEMM blocks [0,512): bid = tt*8 + ks  (XCD = bid%8 = ks -> all blocks sharing
// a W K-slice land on one XCD's L2). Thread = 1 token, 64 expert accs, K-slice
// of 128. A staged coalesced via LDS (read ONCE chip-wide: 32 MB total).
// W loads are wave-uniform -> scalar cache. Compute-bound: ~8192 FMA/thread.
// Fill blocks [512, 4608): grid-stride float4 zero of the 537 MB output;
// HBM-write-bound ~85-90us; the GEMM hides under it.
__global__ __launch_bounds__(NTHR) void k_fused(const float* __restrict__ x,
                                                const float* __restrict__ w,
                                                float* __restrict__ part,  // [8][S][E]
                                                float* __restrict__ out,
                                                float* __restrict__ me_sum) {
    int bid = blockIdx.x;
    int tid = threadIdx.x;
    if (bid < GEMM_BLOCKS) {
        __shared__ float Alds[TOKB][36];   // pad 36: 16B-aligned rows, 18.4 KB
        int tt = bid >> 3;
        int ks = bid & 7;
        int t0 = tt * TOKB;
        int kb0 = ks * 128;
        float4 acc4[16];
#pragma unroll
        for (int i = 0; i < 16; ++i) acc4[i] = make_float4(0.f, 0.f, 0.f, 0.f);
        for (int sub = 0; sub < 4; ++sub) {
            int kbase = kb0 + sub * 32;
            // stage 128 tok x 32 k, coalesced (8 lanes = 128B contiguous)
#pragma unroll
            for (int it = 0; it < 8; ++it) {
                int r = (tid >> 3) + 16 * it;
                int c = (tid & 7) * 4;
                float4 v = *(const float4*)(x + (size_t)(t0 + r) * Dm + kbase + c);
                *(float4*)&Alds[r][c] = v;
            }
            __syncthreads();
            for (int kk = 0; kk < 32; kk += 4) {
                float4 a = *(const float4*)&Alds[tid][kk];
                const float* wk = w + kbase + kk;
#pragma unroll
                for (int eg = 0; eg < 16; ++eg) {   // full unroll: acc stays in regs
                    float4 w0 = *(const float4*)(wk + (size_t)(eg * 4 + 0) * Dm);
                    float4 w1 = *(const float4*)(wk + (size_t)(eg * 4 + 1) * Dm);
                    float4 w2 = *(const float4*)(wk + (size_t)(eg * 4 + 2) * Dm);
                    float4 w3 = *(const float4*)(wk + (size_t)(eg * 4 + 3) * Dm);
                    acc4[eg].x = fmaf(a.w, w0.w, fmaf(a.z, w0.z, fmaf(a.y, w0.y, fmaf(a.x, w0.x, acc4[eg].x))));
                    acc4[eg].y = fmaf(a.w, w1.w, fmaf(a.z, w1.z, fmaf(a.y, w1.y, fmaf(a.x, w1.x, acc4[eg].y))));
                    acc4[eg].z = fmaf(a.w, w2.w, fmaf(a.z, w2.z, fmaf(a.y, w2.y, fmaf(a.x, w2.x, acc4[eg].z))));
                    acc4[eg].w = fmaf(a.w, w3.w, fmaf(a.z, w3.z, fmaf(a.y, w3.y, fmaf(a.x, w3.x, acc4[eg].w))));
                }
            }
            __syncthreads();
        }
        float* prow = part + ((size_t)ks * S + (t0 + tid)) * E;
#pragma unroll
        for (int eg = 0; eg < 16; ++eg)
            *(float4*)(prow + eg * 4) = acc4[eg];
    } else {
        int fb = bid - GEMM_BLOCKS;
        if (fb == 0 && tid < E) me_sum[tid] = 0.f;
        const unsigned N4 = (unsigned)((1ull + 2ull * SEC + 64ull) / 4ull);  // 33,554,448
        float4 z = make_float4(0.f, 0.f, 0.f, 0.f);
        float4* o4 = (float4*)out;
        for (unsigned i = (unsigned)fb * NTHR + tid; i < N4; i += FILL_BLOCKS * NTHR)
            o4[i] = z;
    }
}

// ---------------- K2: partial-reduce + softmax/argmax + column sums ----------
// 128 blocks x 64 threads; reduces the 8 K-partials during the (coalesced)
// load, then 64x64 tile softmax as before.
__global__ __launch_bounds__(64) void k_softmax(const float* __restrict__ part,
                                                float* __restrict__ gate,
                                                int* __restrict__ idx,
                                                float* __restrict__ me_sum) {
    __shared__ float tile[64][65];
    __shared__ float sm[64];
    __shared__ float sinv[64];
    int t0 = blockIdx.x * 64;
    int tid = threadIdx.x;
    for (int it = 0; it < 16; ++it) {
        int row = it * 4 + (tid >> 4);
        int c4 = (tid & 15) * 4;
        size_t off = (size_t)(t0 + row) * E + c4;
        float4 v = *(const float4*)(part + off);
#pragma unroll
        for (int ks = 1; ks < 8; ++ks) {
            float4 u = *(const float4*)(part + (size_t)ks * S * E + off);
            v.x += u.x; v.y += u.y; v.z += u.z; v.w += u.w;
        }
        tile[row][c4 + 0] = v.x;
        tile[row][c4 + 1] = v.y;
        tile[row][c4 + 2] = v.z;
        tile[row][c4 + 3] = v.w;
    }
    __syncthreads();
    {   // row phase: first-index argmax + exp-sum
        int r = tid;
        float m = tile[r][0];
        int am = 0;
#pragma unroll
        for (int c = 1; c < E; ++c) {
            float v = tile[r][c];
            if (v > m) { m = v; am = c; }
        }
        float ssum = 0.f;
#pragma unroll
        for (int c = 0; c < E; ++c) ssum += __expf(tile[r][c] - m);
        float inv = 1.0f / ssum;
        gate[t0 + r] = inv;
        idx[t0 + r] = am;
        sm[r] = m;
        sinv[r] = inv;
    }
    __syncthreads();
    {   // column phase: per-expert softmax column sums (for me)
        int c = tid;
        float cs = 0.f;
#pragma unroll 8
        for (int r = 0; r < 64; ++r) cs += __expf(tile[r][c] - sm[r]) * sinv[r];
        atomicAdd(&me_sum[c], cs);
    }
}

// ---------------- K3: ordered scan + scatter + counts + l_aux ----------------
__global__ __launch_bounds__(256) void k_scan(const int* __restrict__ idx,
                                              const float* __restrict__ gate,
                                              const float* __restrict__ me_sum,
                                              float* __restrict__ out) {
    int e = blockIdx.x;
    int tid = threadIdx.x;
    int lane = tid & 63;
    int wid = tid >> 6;
    __shared__ int wsum[4];
    int running = 0;
    for (int ch = 0; ch < S / 256; ++ch) {
        int t = ch * 256 + tid;
        bool f = (idx[t] == e);
        unsigned long long b = __ballot(f);
        int pre = __popcll(b & ((1ull << lane) - 1ull));
        if (lane == 0) wsum[wid] = __popcll(b);
        __syncthreads();
        int off = running;
#pragma unroll
        for (int w2 = 0; w2 < 4; ++w2)
            if (w2 < wid) off += wsum[w2];
        int p = off + pre;
        if (f && p < CAP) {
            size_t o = 1 + (size_t)t * (E * CAP) + (size_t)e * CAP + (size_t)p;
            out[o] = gate[t];                 // combine_weights
            out[o + (size_t)SEC] = 1.0f;      // dispatch_mask
        }
        running += wsum[0] + wsum[1] + wsum[2] + wsum[3];
        __syncthreads();
    }
    if (tid == 0) {
        out[1 + 2 * (size_t)SEC + e] = (float)running;   // exp_counts (pre-drop)
        float la = me_sum[e] * (1.0f / (float)S) *
                   ((float)running / (float)S) * (float)E;
        atomicAdd(out, la);                              // l_aux
    }
}

extern "C" void kernel_launch(void* const* d_in, const int* in_sizes, int n_in,
                              void* d_out, int out_size, void* d_ws, size_t ws_size,
                              hipStream_t stream) {
    const float* x = (const float*)d_in[0];      // [S, Dm] fp32
    const float* w = (const float*)d_in[1];      // [E, Dm] fp32
    float* out = (float*)d_out;

    // ws layout
    float* part = (float*)d_ws;                  // [8][S][E] = 16 MB
    float* gate = part + 8ull * S * E;           // S floats
    int* idx = (int*)(gate + S);                 // S ints
    float* me_sum = (float*)(idx + S);           // E floats

    k_fused<<<dim3(GEMM_BLOCKS + FILL_BLOCKS), dim3(NTHR), 0, stream>>>(
        x, w, part, out, me_sum);
    k_softmax<<<dim3(128), dim3(64), 0, stream>>>(part, gate, idx, me_sum);
    k_scan<<<dim3(64), dim3(256), 0, stream>>>(idx, gate, me_sum, out);
}

// Round 4
// 185.524 us; speedup vs baseline: 1.3620x; 1.3620x over previous
//
#include <hip/hip_runtime.h>
#include <cstdint>
#include <cstddef>

#define S 8192
#define Dm 1024
#define E 64
#define CAP 128
#define SEC 67108864ull   // S*E*CAP
// out layout (float32 elements):
//   [0] l_aux | [1,1+SEC) combine | [1+SEC,1+2SEC) dispatch | [1+2SEC,+64) counts
// out_size = 1 + 2*SEC + 64 = 134,217,793. Fill covers the first 134,217,792;
// the one leftover element is exp_counts[63], written unconditionally by k_scan.

#define GEMM_BLOCKS 256   // 32 tokens x 64 experts each
#define FILL_BLOCKS 2048
#define PAD 66            // LDS row pad (floats): 2*tok bank stride -> 2-way max

// ---------------- K1: fused {GEMM+softmax+argmax} + 537MB zero-fill ----------
// GEMM blocks [0,256): thread = (token tid&31, expert-octet tid>>5).
//   A[32][64] chunk staged coalesced in LDS (A read ONCE chip-wide: 32 MB).
//   W float4 loads are half-wave-uniform -> single L1 transaction, W (256 KB)
//   stays hot in L1/L2. 8 scalar accs/thread -> no spill (R3 lesson).
//   Epilogue: block holds full logit rows -> softmax/argmax/col-sums in LDS.
// Fill blocks [256,2304): grid-stride float4 zero of the 537 MB output
//   (HBM-write-bound ~85us); the GEMM+softmax hides under it.
__global__ __launch_bounds__(256) void k_main(const float* __restrict__ x,
                                              const float* __restrict__ w,
                                              float* __restrict__ gate,
                                              int* __restrict__ idx,
                                              float* __restrict__ me_part,
                                              float* __restrict__ out) {
    int bid = blockIdx.x;
    int tid = threadIdx.x;
    if (bid < GEMM_BLOCKS) {
        __shared__ float lds[32][PAD];
        __shared__ float sm[32];
        __shared__ float sinv[32];
        int tok = tid & 31;         // local token
        int eo = tid >> 5;          // expert octet 0..7
        int t0 = bid * 32;
        // staging map: row tid>>3 (0..31), 8 floats at col (tid&7)*8
        const float* asrc = x + (size_t)(t0 + (tid >> 3)) * Dm + (tid & 7) * 8;
        float* adst = &lds[tid >> 3][(tid & 7) * 8];
        const float* wp = w + (size_t)eo * 8 * Dm;
        float acc[8] = {0.f, 0.f, 0.f, 0.f, 0.f, 0.f, 0.f, 0.f};
        for (int ch = 0; ch < 16; ++ch) {
            int kb = ch * 64;
            float4 a0 = *(const float4*)(asrc + kb);
            float4 a1 = *(const float4*)(asrc + kb + 4);
            *(float2*)(adst + 0) = make_float2(a0.x, a0.y);
            *(float2*)(adst + 2) = make_float2(a0.z, a0.w);
            *(float2*)(adst + 4) = make_float2(a1.x, a1.y);
            *(float2*)(adst + 6) = make_float2(a1.z, a1.w);
            __syncthreads();
#pragma unroll 2
            for (int k4 = 0; k4 < 16; ++k4) {
                float2 aa = *(const float2*)&lds[tok][k4 * 4];
                float2 ab = *(const float2*)&lds[tok][k4 * 4 + 2];
                const float* wk = wp + kb + k4 * 4;
#pragma unroll
                for (int j = 0; j < 8; ++j) {
                    float4 wv = *(const float4*)(wk + (size_t)j * Dm);
                    acc[j] = fmaf(ab.y, wv.w, fmaf(ab.x, wv.z,
                             fmaf(aa.y, wv.y, fmaf(aa.x, wv.x, acc[j]))));
                }
            }
            __syncthreads();
        }
        // ---- epilogue: logits tile -> LDS, softmax/argmax/col-sums ----
#pragma unroll
        for (int j = 0; j < 8; ++j) lds[tok][eo * 8 + j] = acc[j];
        __syncthreads();
        if (tid < 32) {   // row phase: first-index argmax + exp-sum
            float m = lds[tid][0];
            int am = 0;
#pragma unroll
            for (int c = 1; c < E; ++c) {
                float v = lds[tid][c];
                if (v > m) { m = v; am = c; }
            }
            float ssum = 0.f;
#pragma unroll
            for (int c = 0; c < E; ++c) ssum += __expf(lds[tid][c] - m);
            float inv = 1.0f / ssum;   // softmax value at the argmax
            gate[t0 + tid] = inv;
            idx[t0 + tid] = am;
            sm[tid] = m;
            sinv[tid] = inv;
        }
        __syncthreads();
        if (tid < E) {    // column phase: partial me sums (deterministic)
            float cs = 0.f;
#pragma unroll 8
            for (int r = 0; r < 32; ++r)
                cs += __expf(lds[r][tid] - sm[r]) * sinv[r];
            me_part[bid * E + tid] = cs;
        }
    } else {
        int fb = bid - GEMM_BLOCKS;
        const unsigned N4 = (unsigned)((1ull + 2ull * SEC + 64ull) / 4ull);  // 33,554,448
        float4 z = make_float4(0.f, 0.f, 0.f, 0.f);
        float4* o4 = (float4*)out;
        for (unsigned i = (unsigned)fb * 256u + tid; i < N4; i += FILL_BLOCKS * 256u)
            o4[i] = z;
    }
}

// ---------------- K2: ordered scan + scatter + counts + me-reduce + l_aux ----
// 64 blocks (one per expert) x 256 threads; deterministic ballot scan in
// token order; scatters combine/dispatch inline (out already zeroed by K1).
__global__ __launch_bounds__(256) void k_scan(const int* __restrict__ idx,
                                              const float* __restrict__ gate,
                                              const float* __restrict__ me_part,
                                              float* __restrict__ out) {
    int e = blockIdx.x;
    int tid = threadIdx.x;
    int lane = tid & 63;
    int wid = tid >> 6;
    __shared__ int wsum[4];
    __shared__ float red[256];
    int running = 0;
    for (int ch = 0; ch < S / 256; ++ch) {
        int t = ch * 256 + tid;
        bool f = (idx[t] == e);
        unsigned long long b = __ballot(f);
        int pre = __popcll(b & ((1ull << lane) - 1ull));
        if (lane == 0) wsum[wid] = __popcll(b);
        __syncthreads();
        int off = running;
#pragma unroll
        for (int w2 = 0; w2 < 4; ++w2)
            if (w2 < wid) off += wsum[w2];
        int p = off + pre;
        if (f && p < CAP) {
            size_t o = 1 + (size_t)t * (E * CAP) + (size_t)e * CAP + (size_t)p;
            out[o] = gate[t];                 // combine_weights
            out[o + (size_t)SEC] = 1.0f;      // dispatch_mask
        }
        running += wsum[0] + wsum[1] + wsum[2] + wsum[3];
        __syncthreads();
    }
    // me reduction: me_sum[e] = sum over 256 blocks' partials
    red[tid] = me_part[tid * E + e];
    __syncthreads();
    for (int s2 = 128; s2 > 0; s2 >>= 1) {
        if (tid < s2) red[tid] += red[tid + s2];
        __syncthreads();
    }
    if (tid == 0) {
        out[1 + 2 * (size_t)SEC + e] = (float)running;   // exp_counts (pre-drop)
        float la = red[0] * (1.0f / (float)S) *
                   ((float)running / (float)S) * (float)E;
        atomicAdd(out, la);                              // l_aux
    }
}

extern "C" void kernel_launch(void* const* d_in, const int* in_sizes, int n_in,
                              void* d_out, int out_size, void* d_ws, size_t ws_size,
                              hipStream_t stream) {
    const float* x = (const float*)d_in[0];      // [S, Dm] fp32
    const float* w = (const float*)d_in[1];      // [E, Dm] fp32
    float* out = (float*)d_out;

    // ws layout
    float* me_part = (float*)d_ws;               // [256][64] floats = 64 KB
    float* gate = me_part + GEMM_BLOCKS * E;     // S floats
    int* idx = (int*)(gate + S);                 // S ints

    k_main<<<dim3(GEMM_BLOCKS + FILL_BLOCKS), dim3(256), 0, stream>>>(
        x, w, gate, idx, me_part, out);
    k_scan<<<dim3(64), dim3(256), 0, stream>>>(idx, gate, me_part, out);
}

// Round 5
// 140.788 us; speedup vs baseline: 1.7948x; 1.3178x over previous
//
#include <hip/hip_runtime.h>
#include <cstdint>
#include <cstddef>

#define S 8192
#define Dm 1024
#define E 64
#define CAP 128
#define SEC 67108864ull   // S*E*CAP
// out layout (float32 elements):
//   [0] l_aux | [1,1+SEC) combine | [1+SEC,1+2SEC) dispatch | [1+2SEC,+64) counts
// out_size = 1 + 2*SEC + 64 = 134,217,793. Fill covers the first 134,217,792;
// the leftover element is exp_counts[63], written unconditionally by k_scan.

#define GEMM_BLOCKS 256   // 32 tokens x 64 experts each
#define FILL_BLOCKS 2048

// ---------------- K1: fused {GEMM+softmax+argmax} + 537MB zero-fill ----------
// GEMM blocks [0,256): thread = (token tid&31, expert-octet tid>>5).
//   Per 64-K chunk, BOTH A (32x64, 8KB) and W (64x64, 16KB) are staged in LDS;
//   the inner loop is LDS-only (immune to the fill's L2 thrash — R4 lesson).
//   Next chunk's 6 global float4 loads are issued right after the LDS-ready
//   barrier (T14 async-stage): ~1000cy HBM latency hides under ~1700cy compute.
//   Epilogue: block holds full logit rows -> softmax/argmax/col-sums in LDS.
// Fill blocks [256,2304): grid-stride float4 zero of the 537 MB output
//   (HBM-write-bound ~81us); the GEMM+softmax hides under it.
__global__ __launch_bounds__(256) void k_main(const float* __restrict__ x,
                                              const float* __restrict__ w,
                                              float* __restrict__ gate,
                                              int* __restrict__ idx,
                                              float* __restrict__ me_part,
                                              float* __restrict__ out) {
    int bid = blockIdx.x;
    int tid = threadIdx.x;
    if (bid < GEMM_BLOCKS) {
        __shared__ float Al[32][66];   // row 264B: float2-aligned, 2-way max
        __shared__ float Wl[64][68];   // row 272B: float4-aligned, 2-way max
        __shared__ float sm[32];
        __shared__ float sinv[32];
        int tok = tid & 31;            // local token
        int eo = tid >> 5;             // expert octet 0..7
        int t0 = bid * 32;
        // staging maps: thread -> row tid>>3, 8 floats at col (tid&7)*8
        const float* asrc = x + (size_t)(t0 + (tid >> 3)) * Dm + (tid & 7) * 8;
        const float* wsrc0 = w + (size_t)(tid >> 3) * Dm + (tid & 7) * 8;
        const float* wsrc1 = wsrc0 + 32 * (size_t)Dm;
        float* adst = &Al[tid >> 3][(tid & 7) * 8];
        float* wdst0 = &Wl[tid >> 3][(tid & 7) * 8];
        float* wdst1 = &Wl[32 + (tid >> 3)][(tid & 7) * 8];

        float acc[8] = {0.f, 0.f, 0.f, 0.f, 0.f, 0.f, 0.f, 0.f};
        // prefetch registers (6 float4)
        float4 pa0 = *(const float4*)(asrc + 0);
        float4 pa1 = *(const float4*)(asrc + 4);
        float4 pw0 = *(const float4*)(wsrc0 + 0);
        float4 pw1 = *(const float4*)(wsrc0 + 4);
        float4 pw2 = *(const float4*)(wsrc1 + 0);
        float4 pw3 = *(const float4*)(wsrc1 + 4);

        for (int ch = 0; ch < 16; ++ch) {
            __syncthreads();           // previous compute done; LDS writable
            // regs -> LDS (A as float2: 264B rows are only 8B-aligned)
            *(float2*)(adst + 0) = make_float2(pa0.x, pa0.y);
            *(float2*)(adst + 2) = make_float2(pa0.z, pa0.w);
            *(float2*)(adst + 4) = make_float2(pa1.x, pa1.y);
            *(float2*)(adst + 6) = make_float2(pa1.z, pa1.w);
            *(float4*)(wdst0 + 0) = pw0;
            *(float4*)(wdst0 + 4) = pw1;
            *(float4*)(wdst1 + 0) = pw2;
            *(float4*)(wdst1 + 4) = pw3;
            __syncthreads();           // LDS ready
            if (ch < 15) {             // issue next chunk's loads (latency hidden)
                int kb = (ch + 1) * 64;
                pa0 = *(const float4*)(asrc + kb);
                pa1 = *(const float4*)(asrc + kb + 4);
                pw0 = *(const float4*)(wsrc0 + kb);
                pw1 = *(const float4*)(wsrc0 + kb + 4);
                pw2 = *(const float4*)(wsrc1 + kb);
                pw3 = *(const float4*)(wsrc1 + kb + 4);
            }
            // LDS-only inner loop: per k4 = 2 b64 (A) + 8 b128 (W, half-wave
            // broadcast) + 32 FMA
#pragma unroll 4
            for (int k4 = 0; k4 < 16; ++k4) {
                float2 aa = *(const float2*)&Al[tok][k4 * 4];
                float2 ab = *(const float2*)&Al[tok][k4 * 4 + 2];
#pragma unroll
                for (int j = 0; j < 8; ++j) {
                    float4 wv = *(const float4*)&Wl[eo * 8 + j][k4 * 4];
                    acc[j] = fmaf(ab.y, wv.w, fmaf(ab.x, wv.z,
                             fmaf(aa.y, wv.y, fmaf(aa.x, wv.x, acc[j]))));
                }
            }
        }
        __syncthreads();
        // ---- epilogue: logits tile -> LDS (reuse Al), softmax/argmax ----
#pragma unroll
        for (int j = 0; j < 8; ++j) Al[tok][eo * 8 + j] = acc[j];
        __syncthreads();
        if (tid < 32) {   // row phase: first-index argmax + exp-sum
            float m = Al[tid][0];
            int am = 0;
#pragma unroll
            for (int c = 1; c < E; ++c) {
                float v = Al[tid][c];
                if (v > m) { m = v; am = c; }
            }
            float ssum = 0.f;
#pragma unroll
            for (int c = 0; c < E; ++c) ssum += __expf(Al[tid][c] - m);
            float inv = 1.0f / ssum;   // softmax value at the argmax
            gate[t0 + tid] = inv;
            idx[t0 + tid] = am;
            sm[tid] = m;
            sinv[tid] = inv;
        }
        __syncthreads();
        if (tid < E) {    // column phase: partial me sums (deterministic)
            float cs = 0.f;
#pragma unroll 8
            for (int r = 0; r < 32; ++r)
                cs += __expf(Al[r][tid] - sm[r]) * sinv[r];
            me_part[bid * E + tid] = cs;
        }
    } else {
        int fb = bid - GEMM_BLOCKS;
        const unsigned N4 = (unsigned)((1ull + 2ull * SEC + 64ull) / 4ull);  // 33,554,448
        float4 z = make_float4(0.f, 0.f, 0.f, 0.f);
        float4* o4 = (float4*)out;
        for (unsigned i = (unsigned)fb * 256u + tid; i < N4; i += FILL_BLOCKS * 256u)
            o4[i] = z;
    }
}

// ---------------- K2: ordered scan + scatter + counts + me-reduce + l_aux ----
// 64 blocks (one per expert) x 256 threads; deterministic ballot scan in
// token order; scatters combine/dispatch inline (out already zeroed by K1).
__global__ __launch_bounds__(256) void k_scan(const int* __restrict__ idx,
                                              const float* __restrict__ gate,
                                              const float* __restrict__ me_part,
                                              float* __restrict__ out) {
    int e = blockIdx.x;
    int tid = threadIdx.x;
    int lane = tid & 63;
    int wid = tid >> 6;
    __shared__ int wsum[4];
    __shared__ float red[256];
    int running = 0;
    for (int ch = 0; ch < S / 256; ++ch) {
        int t = ch * 256 + tid;
        bool f = (idx[t] == e);
        unsigned long long b = __ballot(f);
        int pre = __popcll(b & ((1ull << lane) - 1ull));
        if (lane == 0) wsum[wid] = __popcll(b);
        __syncthreads();
        int off = running;
#pragma unroll
        for (int w2 = 0; w2 < 4; ++w2)
            if (w2 < wid) off += wsum[w2];
        int p = off + pre;
        if (f && p < CAP) {
            size_t o = 1 + (size_t)t * (E * CAP) + (size_t)e * CAP + (size_t)p;
            out[o] = gate[t];                 // combine_weights
            out[o + (size_t)SEC] = 1.0f;      // dispatch_mask
        }
        running += wsum[0] + wsum[1] + wsum[2] + wsum[3];
        __syncthreads();
    }
    // me reduction: me_sum[e] = sum over 256 blocks' partials
    red[tid] = me_part[tid * E + e];
    __syncthreads();
    for (int s2 = 128; s2 > 0; s2 >>= 1) {
        if (tid < s2) red[tid] += red[tid + s2];
        __syncthreads();
    }
    if (tid == 0) {
        out[1 + 2 * (size_t)SEC + e] = (float)running;   // exp_counts (pre-drop)
        float la = red[0] * (1.0f / (float)S) *
                   ((float)running / (float)S) * (float)E;
        atomicAdd(out, la);                              // l_aux
    }
}

extern "C" void kernel_launch(void* const* d_in, const int* in_sizes, int n_in,
                              void* d_out, int out_size, void* d_ws, size_t ws_size,
                              hipStream_t stream) {
    const float* x = (const float*)d_in[0];      // [S, Dm] fp32
    const float* w = (const float*)d_in[1];      // [E, Dm] fp32
    float* out = (float*)d_out;

    // ws layout
    float* me_part = (float*)d_ws;               // [256][64] floats = 64 KB
    float* gate = me_part + GEMM_BLOCKS * E;     // S floats
    int* idx = (int*)(gate + S);                 // S ints

    k_main<<<dim3(GEMM_BLOCKS + FILL_BLOCKS), dim3(256), 0, stream>>>(
        x, w, gate, idx, me_part, out);
    k_scan<<<dim3(64), dim3(256), 0, stream>>>(idx, gate, me_part, out);
}